// Round 1
// baseline (1331.551 us; speedup 1.0000x reference)
//
#include <hip/hip_runtime.h>
#include <hip/hip_bf16.h>

typedef __bf16 bf16x8 __attribute__((ext_vector_type(8)));
typedef __bf16 bf16x4 __attribute__((ext_vector_type(4)));
typedef float  f32x4  __attribute__((ext_vector_type(4)));

#define HW_   3136            // 56*56
#define NPIX  200704          // 64*56*56
#define GI_ELEMS 25690112     // NPIX*128

__device__ __forceinline__ f32x4 mfma16(bf16x8 a, bf16x8 b, f32x4 c){
  return __builtin_amdgcn_mfma_f32_16x16x32_bf16(a, b, c, 0, 0, 0);
}

// ---------------- std_kernels fp32 -> bf16 ----------------
__global__ __launch_bounds__(256) void k_cvt(const float* __restrict__ s, __bf16* __restrict__ d){
  const int i = (blockIdx.x*256 + threadIdx.x)*4;
  f32x4 x = *(const f32x4*)(s + i);
  bf16x4 y;
  #pragma unroll
  for (int e=0;e<4;e++) y[e] = (__bf16)x[e];
  *(bf16x4*)(d + i) = y;
}

// ---------------- go -> goT (bf16 [co][pix]) + bias partials ----------------
__global__ __launch_bounds__(256) void k_goT(const float* __restrict__ go,
                                             __bf16* __restrict__ goT,
                                             float* __restrict__ biasA){
  __shared__ __bf16 ldsT[128][72];
  __shared__ float biasS[128];
  const int t = threadIdx.x;
  const size_t p0 = (size_t)blockIdx.x*64;
  if (t < 128) biasS[t] = 0.f;
  __syncthreads();
  float bs[4] = {0.f,0.f,0.f,0.f};
  const int co0 = (t*4) & 127;
  #pragma unroll
  for (int i=0;i<8;i++){
    const int flat = (i*256+t)*4;
    const int pl = flat >> 7; const int co = flat & 127;
    f32x4 x = *(const f32x4*)(go + p0*128 + flat);
    #pragma unroll
    for (int e=0;e<4;e++){ ldsT[co+e][pl] = (__bf16)x[e]; bs[e] += x[e]; }
  }
  #pragma unroll
  for (int e=0;e<4;e++) atomicAdd(&biasS[co0+e], bs[e]);
  __syncthreads();
  #pragma unroll
  for (int j=0;j<2;j++){
    const int task = t + j*256; const int co = task>>2; const int ch = task&3;
    bf16x8 v0 = *(const bf16x8*)&ldsT[co][ch*16];
    bf16x8 v1 = *(const bf16x8*)&ldsT[co][ch*16+8];
    __bf16* d = goT + (size_t)co*NPIX + p0 + ch*16;
    *(bf16x8*)d = v0; *(bf16x8*)(d+8) = v1;
  }
  if (t < 128) atomicAdd(&biasA[t], biasS[t]);
}

// ---------------- inputs -> inTpad (bf16 [ci][b][58][64], interior at [h+1][w]) ----------------
__global__ __launch_bounds__(256) void k_inT(const float* __restrict__ inp,
                                             __bf16* __restrict__ inT){
  __shared__ float ldsT[128][72];
  const int t = threadIdx.x;
  const size_t p0 = (size_t)blockIdx.x*64;
  #pragma unroll
  for (int i=0;i<8;i++){
    const int flat = (i*256+t)*4;
    const int pl = flat >> 7; const int ci = flat & 127;
    f32x4 x = *(const f32x4*)(inp + p0*128 + flat);
    #pragma unroll
    for (int e=0;e<4;e++) ldsT[ci+e][pl] = x[e];
  }
  __syncthreads();
  #pragma unroll
  for (int j=0;j<4;j++){
    const int task = t + j*256; const int ci = task>>3; const int ch = task&7;
    const int p = (int)p0 + ch*8;
    const int b = p / HW_; const int r = p - b*HW_;
    const int h = r / 56;  const int w = r - h*56;
    bf16x8 pk;
    #pragma unroll
    for (int e=0;e<8;e++) pk[e] = (__bf16)ldsT[ci][ch*8+e];
    *(bf16x8*)(inT + (((size_t)(ci*64+b))*58 + (h+1))*64 + w) = pk;
  }
}

// ---------------- grad_in: [64 px/block] x [128 ci], MFMA, frags direct from global ----------------
__global__ __launch_bounds__(256) void k_gradin(const float* __restrict__ go,
                                                const __bf16* __restrict__ stdkb,
                                                float* __restrict__ out){
  const int tid = threadIdx.x;
  const int wv = tid >> 6, l = tid & 63, lr = l & 15, lg = l >> 4;
  const int ptile = blockIdx.x*64 + wv*16;
  f32x4 acc[8];
  #pragma unroll
  for (int j=0;j<8;j++){
    #pragma unroll
    for (int r=0;r<4;r++) acc[j][r] = 0.f;
  }
  const int p = ptile + lr;
  const int b = p / HW_; const int rem = p - b*HW_;
  const int h = rem / 56; const int w = rem - h*56;

  for (int u=0; u<3; u++){
    const int hs = h + 1 - u;
    for (int v=0; v<3; v++){
      const int wsrc = w + 1 - v;
      const bool valid = ((unsigned)hs < 56u) & ((unsigned)wsrc < 56u);
      const float* src = go + (size_t)((b*56 + hs)*56 + wsrc) * 128;
      const __bf16* wb = stdkb + (size_t)(u*3+v) * 16384;
      #pragma unroll
      for (int kc=0; kc<4; kc++){
        const int co0 = kc*32 + lg*8;
        bf16x8 afrag;
        if (valid){
          f32x4 x0 = *(const f32x4*)(src + co0);
          f32x4 x1 = *(const f32x4*)(src + co0 + 4);
          #pragma unroll
          for (int e=0;e<4;e++){ afrag[e] = (__bf16)x0[e]; afrag[e+4] = (__bf16)x1[e]; }
        } else {
          #pragma unroll
          for (int e=0;e<8;e++) afrag[e] = (__bf16)0.f;
        }
        #pragma unroll
        for (int j=0;j<8;j++){
          bf16x8 bfrag = *(const bf16x8*)(wb + (size_t)(j*16 + lr)*128 + co0);
          acc[j] = mfma16(afrag, bfrag, acc[j]);
        }
      }
    }
  }
  float* o = out + (size_t)ptile*128;
  #pragma unroll
  for (int j=0;j<8;j++){
    #pragma unroll
    for (int r=0;r<4;r++)
      o[(size_t)(4*lg + r)*128 + j*16 + lr] = acc[j][r];
  }
}

// ---------------- grad_wt_raw: split-K (1 image/block), MFMA, atomic accumulate ----------------
__global__ __launch_bounds__(256) void k_gradwt(const __bf16* __restrict__ inT,
                                                const __bf16* __restrict__ goT,
                                                float* __restrict__ raw){
  const int tid = threadIdx.x;
  const int wv = tid >> 6, l = tid & 63, lr = l & 15, lg = l >> 4;
  const int tap = blockIdx.z; const int u = tap/3, v = tap - u*3;
  const int ci0 = blockIdx.y*64 + wv*16;
  const int bimg = blockIdx.x;
  f32x4 acc[8];
  #pragma unroll
  for (int j=0;j<8;j++){
    #pragma unroll
    for (int r=0;r<4;r++) acc[j][r] = 0.f;
  }
  const int ci = ci0 + lr;
  const size_t abase = ((size_t)(ci*64 + bimg))*58;
  for (int ks=0; ks<98; ks++){
    const int rem = ks*32 + lg*8;
    const int h = rem / 56; const int w0 = rem - h*56;
    const __bf16* as = inT + (abase + (h+u))*64 + (w0 + v - 1);
    bf16x8 afrag;
    #pragma unroll
    for (int e=0;e<8;e++) afrag[e] = as[e];
    const int pix0 = bimg*HW_ + rem;
    #pragma unroll
    for (int j=0;j<8;j++){
      bf16x8 bfrag = *(const bf16x8*)(goT + (size_t)(j*16 + lr)*NPIX + pix0);
      acc[j] = mfma16(afrag, bfrag, acc[j]);
    }
  }
  #pragma unroll
  for (int j=0;j<8;j++){
    #pragma unroll
    for (int r=0;r<4;r++)
      atomicAdd(&raw[(size_t)(tap*128 + ci0 + 4*lg + r)*128 + j*16 + lr], acc[j][r]);
  }
}

// ---------------- weight-standardization backward chain + bias/gain ----------------
__global__ __launch_bounds__(128) void k_std(const float* __restrict__ raw,
      const float* __restrict__ kern, const float* __restrict__ gain,
      const float* __restrict__ bmap, const float* __restrict__ biasA,
      float* __restrict__ out_wt, float* __restrict__ out_bias, float* __restrict__ out_gain){
  const int co = blockIdx.x, t = threadIdx.x;
  float kv[9], gv[9];
  float s1=0.f, s2=0.f, sg=0.f, sgk=0.f;
  #pragma unroll
  for (int i=0;i<9;i++){
    const int m = t + i*128;
    const float k_ = kern[(size_t)m*128 + co];
    const float g_ = raw [(size_t)m*128 + co];
    kv[i]=k_; gv[i]=g_;
    s1 += k_; s2 += k_*k_; sg += g_; sgk += g_*k_;
  }
  __shared__ float red[4][128];
  red[0][t]=s1; red[1][t]=s2; red[2][t]=sg; red[3][t]=sgk;
  __syncthreads();
  for (int off=64; off>0; off>>=1){
    if (t < off){
      red[0][t]+=red[0][t+off]; red[1][t]+=red[1][t+off];
      red[2][t]+=red[2][t+off]; red[3][t]+=red[3][t+off];
    }
    __syncthreads();
  }
  const float N = 1152.f;
  const float S1=red[0][0], S2=red[1][0], Sg=red[2][0], Sgk=red[3][0];
  const float mu = S1/N;
  const float var = S2/N - mu*mu;
  const float mvar = N*var;
  const float maxvar = fmaxf(mvar, 1e-4f);
  const float sqrtvar = sqrtf(maxvar);
  const float ivar = 1.f/sqrtvar;
  const float g = gain[co];
  const float givar = g*ivar;
  const float dgivar = Sgk - mu*Sg;          // sum(grad * xmu)
  const float divar = dgivar*g;
  const float dsqrtvar = -divar/maxvar;
  const float dmaxvar = 0.5f*dsqrtvar/sqrtvar;
  const float dsq = bmap[co]*dmaxvar;        // == dmvar == dsq (dvar=N*dmvar, dsq=dvar/N)
  const float dmu = -(givar*Sg + 2.f*dsq*(S1 - N*mu));
  const float dmuN = dmu*(1.f/N);
  #pragma unroll
  for (int i=0;i<9;i++){
    const int m = t + i*128;
    out_wt[(size_t)m*128 + co] = gv[i]*givar + 2.f*(kv[i]-mu)*dsq + dmuN;
  }
  if (t == 0){ out_gain[co] = dgivar*ivar; out_bias[co] = biasA[co]; }
}

extern "C" void kernel_launch(void* const* d_in, const int* in_sizes, int n_in,
                              void* d_out, int out_size, void* d_ws, size_t ws_size,
                              hipStream_t stream){
  const float* go   = (const float*)d_in[0];
  const float* inp  = (const float*)d_in[1];
  const float* kern = (const float*)d_in[2];
  const float* stdk = (const float*)d_in[3];
  const float* gain = (const float*)d_in[4];
  const float* bmap = (const float*)d_in[5];

  char* ws = (char*)d_ws;
  __bf16* goT   = (__bf16*)(ws + 0);                 // 51,380,224 B
  float*  raw   = (float*) (ws + 51380224);          //    589,824 B
  float*  biasA = (float*) (ws + 51970048);          //        512 B
  __bf16* stdkb = (__bf16*)(ws + 51970560);          //    294,912 B
  char*   guard =           ws + 52265472;           //        256 B (zero guard before inT)
  __bf16* inT   = (__bf16*)(ws + 52265728);          // 60,817,408 B  (total ~113.1 MB)

  hipMemsetAsync(raw,   0, 589824, stream);
  hipMemsetAsync(biasA, 0, 512, stream);
  hipMemsetAsync(guard, 0, 256 + 60817408, stream);  // guard + full padded input

  k_cvt   <<<144, 256, 0, stream>>>(stdk, stdkb);
  k_goT   <<<3136, 256, 0, stream>>>(go, goT, biasA);
  k_inT   <<<3136, 256, 0, stream>>>(inp, inT);
  k_gradin<<<3136, 256, 0, stream>>>(go, stdkb, (float*)d_out);
  k_gradwt<<<dim3(64,2,9), 256, 0, stream>>>(inT, goT, raw);

  float* out = (float*)d_out;
  k_std<<<128, 128, 0, stream>>>(raw, kern, gain, bmap, biasA,
                                 out + GI_ELEMS,
                                 out + GI_ELEMS + 147456,
                                 out + GI_ELEMS + 147456 + 128);
}

// Round 2
// 831.164 us; speedup vs baseline: 1.6020x; 1.6020x over previous
//
#include <hip/hip_runtime.h>
#include <hip/hip_bf16.h>

typedef __bf16 bf16x8 __attribute__((ext_vector_type(8)));
typedef __bf16 bf16x4 __attribute__((ext_vector_type(4)));
typedef float  f32x4  __attribute__((ext_vector_type(4)));
typedef unsigned int u32;

#define HW_   3136            // 56*56
#define NPIX  200704          // 64*56*56
#define GI_ELEMS 25690112     // NPIX*128

__device__ __forceinline__ f32x4 mfma16(bf16x8 a, bf16x8 b, f32x4 c){
  return __builtin_amdgcn_mfma_f32_16x16x32_bf16(a, b, c, 0, 0, 0);
}

__device__ __forceinline__ void async16(const __bf16* g, __bf16* l){
  __builtin_amdgcn_global_load_lds(
      (const __attribute__((address_space(1))) void*)g,
      (__attribute__((address_space(3))) void*)l, 16, 0, 0);
}

// ---------------- std_kernels fp32 -> bf16 ----------------
__global__ __launch_bounds__(256) void k_cvt(const float* __restrict__ s, __bf16* __restrict__ d){
  const int i = (blockIdx.x*256 + threadIdx.x)*4;
  f32x4 x = *(const f32x4*)(s + i);
  bf16x4 y;
  #pragma unroll
  for (int e=0;e<4;e++) y[e] = (__bf16)x[e];
  *(bf16x4*)(d + i) = y;
}

// ---------------- go -> goT (bf16 [co][pix]) + bias partials ----------------
__global__ __launch_bounds__(256) void k_goT(const float* __restrict__ go,
                                             __bf16* __restrict__ goT,
                                             float* __restrict__ biasA){
  __shared__ __bf16 ldsT[128][72];
  __shared__ float biasS[128];
  const int t = threadIdx.x;
  const size_t p0 = (size_t)blockIdx.x*64;
  if (t < 128) biasS[t] = 0.f;
  __syncthreads();
  float bs[4] = {0.f,0.f,0.f,0.f};
  const int co0 = (t*4) & 127;
  #pragma unroll
  for (int i=0;i<8;i++){
    const int flat = (i*256+t)*4;
    const int pl = flat >> 7; const int co = flat & 127;
    f32x4 x = *(const f32x4*)(go + p0*128 + flat);
    #pragma unroll
    for (int e=0;e<4;e++){ ldsT[co+e][pl] = (__bf16)x[e]; bs[e] += x[e]; }
  }
  #pragma unroll
  for (int e=0;e<4;e++) atomicAdd(&biasS[co0+e], bs[e]);
  __syncthreads();
  #pragma unroll
  for (int j=0;j<2;j++){
    const int task = t + j*256; const int co = task>>2; const int ch = task&3;
    bf16x8 v0 = *(const bf16x8*)&ldsT[co][ch*16];
    bf16x8 v1 = *(const bf16x8*)&ldsT[co][ch*16+8];
    __bf16* d = goT + (size_t)co*NPIX + p0 + ch*16;
    *(bf16x8*)d = v0; *(bf16x8*)(d+8) = v1;
  }
  if (t < 128) atomicAdd(&biasA[t], biasS[t]);
}

// ---------------- inputs -> inTpad (bf16 [ci][b][58][64], interior at [h+1][w]) ----------------
__global__ __launch_bounds__(256) void k_inT(const float* __restrict__ inp,
                                             __bf16* __restrict__ inT){
  __shared__ float ldsT[128][72];
  const int t = threadIdx.x;
  const size_t p0 = (size_t)blockIdx.x*64;
  #pragma unroll
  for (int i=0;i<8;i++){
    const int flat = (i*256+t)*4;
    const int pl = flat >> 7; const int ci = flat & 127;
    f32x4 x = *(const f32x4*)(inp + p0*128 + flat);
    #pragma unroll
    for (int e=0;e<4;e++) ldsT[ci+e][pl] = x[e];
  }
  __syncthreads();
  #pragma unroll
  for (int j=0;j<4;j++){
    const int task = t + j*256; const int ci = task>>3; const int ch = task&7;
    const int p = (int)p0 + ch*8;
    const int b = p / HW_; const int r = p - b*HW_;
    const int h = r / 56;  const int w = r - h*56;
    bf16x8 pk;
    #pragma unroll
    for (int e=0;e<8;e++) pk[e] = (__bf16)ldsT[ci][ch*8+e];
    *(bf16x8*)(inT + (((size_t)(ci*64+b))*58 + (h+1))*64 + w) = pk;
  }
}

// ---------------- grad_in: [64 px/block] x [128 ci], MFMA, frags direct from global ----------------
__global__ __launch_bounds__(256) void k_gradin(const float* __restrict__ go,
                                                const __bf16* __restrict__ stdkb,
                                                float* __restrict__ out){
  const int tid = threadIdx.x;
  const int wv = tid >> 6, l = tid & 63, lr = l & 15, lg = l >> 4;
  const int ptile = blockIdx.x*64 + wv*16;
  f32x4 acc[8];
  #pragma unroll
  for (int j=0;j<8;j++){
    #pragma unroll
    for (int r=0;r<4;r++) acc[j][r] = 0.f;
  }
  const int p = ptile + lr;
  const int b = p / HW_; const int rem = p - b*HW_;
  const int h = rem / 56; const int w = rem - h*56;

  for (int u=0; u<3; u++){
    const int hs = h + 1 - u;
    for (int v=0; v<3; v++){
      const int wsrc = w + 1 - v;
      const bool valid = ((unsigned)hs < 56u) & ((unsigned)wsrc < 56u);
      const float* src = go + (size_t)((b*56 + hs)*56 + wsrc) * 128;
      const __bf16* wb = stdkb + (size_t)(u*3+v) * 16384;
      #pragma unroll
      for (int kc=0; kc<4; kc++){
        const int co0 = kc*32 + lg*8;
        bf16x8 afrag;
        if (valid){
          f32x4 x0 = *(const f32x4*)(src + co0);
          f32x4 x1 = *(const f32x4*)(src + co0 + 4);
          #pragma unroll
          for (int e=0;e<4;e++){ afrag[e] = (__bf16)x0[e]; afrag[e+4] = (__bf16)x1[e]; }
        } else {
          #pragma unroll
          for (int e=0;e<8;e++) afrag[e] = (__bf16)0.f;
        }
        #pragma unroll
        for (int j=0;j<8;j++){
          bf16x8 bfrag = *(const bf16x8*)(wb + (size_t)(j*16 + lr)*128 + co0);
          acc[j] = mfma16(afrag, bfrag, acc[j]);
        }
      }
    }
  }
  float* o = out + (size_t)ptile*128;
  #pragma unroll
  for (int j=0;j<8;j++){
    #pragma unroll
    for (int r=0;r<4;r++)
      o[(size_t)(4*lg + r)*128 + j*16 + lr] = acc[j][r];
  }
}

// ---------------- grad_wt_raw v2: all 9 taps per block, LDS double-buffered ----------------
// grid (64 b, 8 cig); block = 16 ci x 128 co x 9 taps; K = 14 chunks of 224 px (4 rows).
// LDS layout (bf16 elems): B0[29696] B1[29696] G0[32] A0[6272] G1[32] A1[6272] = 72000 (144 KB)
// B row stride 232 elems (29 x 16B chunks, chunk 28 = pad); A ci stride 392 (49 chunks, chunk 48 = pad=0).
#define BOFF0 0
#define BOFF1 29696
#define AOFF0 59424
#define AOFF1 65728

__device__ __forceinline__ void stage_chunk(const __bf16* __restrict__ goT,
                                            const __bf16* __restrict__ inT,
                                            const __bf16* __restrict__ zsrc,
                                            __bf16* lds, int boff, int aoff,
                                            int b, int ci0, int c, int w, int l){
  const int pixbase = b*HW_ + c*224;
  const int pr0 = c*4;
  #pragma unroll
  for (int i=0;i<15;++i){
    const int cbase = i*256 + w*64;
    if (cbase < 3712){
      const int chunk = cbase + l;
      const int co = chunk / 29;
      const int part = chunk - co*29;
      const __bf16* src = (part < 28) ? (goT + (size_t)co*NPIX + pixbase + part*8) : zsrc;
      async16(src, lds + boff + cbase*8);
    }
  }
  #pragma unroll
  for (int i=0;i<4;++i){
    const int cbase = i*256 + w*64;
    const int chunk = cbase + l;
    if (chunk < 784){
      const int ci = chunk / 49;
      const int r = chunk - ci*49;
      const __bf16* src = (r < 48)
        ? (inT + (((size_t)((ci0+ci)*64 + b))*58 + (pr0 + (r>>3)))*64 + (r&7)*8)
        : zsrc;
      async16(src, lds + aoff + cbase*8);
    }
  }
}

__global__ __launch_bounds__(256, 1) void k_gradwt2(const __bf16* __restrict__ goT,
                                                    const __bf16* __restrict__ inT,
                                                    const __bf16* __restrict__ zsrc,
                                                    float* __restrict__ raw){
  __shared__ __bf16 LDS[72000];
  const int t = threadIdx.x;
  const int w = t >> 6, l = t & 63, lr = l & 15, lg = l >> 4;
  const int b = blockIdx.x, ci0 = blockIdx.y*16;
  const int wco = w*32;

  // zero the LDS guards (stay zero; staging never writes them)
  if (t < 32){ LDS[AOFF0-32+t] = (__bf16)0.f; LDS[AOFF1-32+t] = (__bf16)0.f; }

  f32x4 acc[9][2];
  #pragma unroll
  for (int tp=0;tp<9;tp++){
    #pragma unroll
    for (int j=0;j<2;j++){
      #pragma unroll
      for (int r=0;r<4;r++) acc[tp][j][r] = 0.f;
    }
  }

  stage_chunk(goT, inT, zsrc, LDS, BOFF0, AOFF0, b, ci0, 0, w, l);
  __syncthreads();

  int buf = 0;
  for (int c=0; c<14; ++c){
    if (c < 13)
      stage_chunk(goT, inT, zsrc, LDS, buf ? BOFF0 : BOFF1, buf ? AOFF0 : AOFF1,
                  b, ci0, c+1, w, l);
    const __bf16* Bb = LDS + (buf ? BOFF1 : BOFF0);
    const __bf16* Ab = LDS + (buf ? AOFF1 : AOFF0);
    #pragma unroll
    for (int ks=0; ks<7; ++ks){
      const int pl = ks*32 + lg*8;
      const int q  = ks*4 + lg;
      const int hl = q / 7;               // 0..3
      const int w0 = pl - hl*56;          // multiple of 8
      bf16x8 b0 = *(const bf16x8*)&Bb[(wco + lr)*232 + pl];
      bf16x8 b1 = *(const bf16x8*)&Bb[(wco + 16 + lr)*232 + pl];
      const __bf16* abase = &Ab[lr*392 + hl*64 + w0];
      #pragma unroll
      for (int u=0; u<3; ++u){
        const __bf16* ap = abase + u*64;
        union { bf16x8 v; u32 d[4]; } va, a0, a2;
        va.v = *(const bf16x8*)ap;
        const u32 m1 = *(const unsigned short*)(ap - 1);
        const u32 p8 = *(const unsigned short*)(ap + 8);
        a0.d[0] = (va.d[0] << 16) | m1;
        a0.d[1] = (va.d[1] << 16) | (va.d[0] >> 16);
        a0.d[2] = (va.d[2] << 16) | (va.d[1] >> 16);
        a0.d[3] = (va.d[3] << 16) | (va.d[2] >> 16);
        a2.d[0] = (va.d[0] >> 16) | (va.d[1] << 16);
        a2.d[1] = (va.d[1] >> 16) | (va.d[2] << 16);
        a2.d[2] = (va.d[2] >> 16) | (va.d[3] << 16);
        a2.d[3] = (va.d[3] >> 16) | (p8 << 16);
        acc[u*3+0][0] = mfma16(a0.v, b0, acc[u*3+0][0]);
        acc[u*3+0][1] = mfma16(a0.v, b1, acc[u*3+0][1]);
        acc[u*3+1][0] = mfma16(va.v, b0, acc[u*3+1][0]);
        acc[u*3+1][1] = mfma16(va.v, b1, acc[u*3+1][1]);
        acc[u*3+2][0] = mfma16(a2.v, b0, acc[u*3+2][0]);
        acc[u*3+2][1] = mfma16(a2.v, b1, acc[u*3+2][1]);
      }
    }
    __syncthreads();
    buf ^= 1;
  }

  #pragma unroll
  for (int tp=0;tp<9;tp++){
    #pragma unroll
    for (int j=0;j<2;j++){
      #pragma unroll
      for (int r=0;r<4;r++)
        atomicAdd(&raw[(size_t)(tp*128 + ci0 + 4*lg + r)*128 + wco + j*16 + lr],
                  acc[tp][j][r]);
    }
  }
}

// ---------------- weight-standardization backward chain + bias/gain ----------------
__global__ __launch_bounds__(128) void k_std(const float* __restrict__ raw,
      const float* __restrict__ kern, const float* __restrict__ gain,
      const float* __restrict__ bmap, const float* __restrict__ biasA,
      float* __restrict__ out_wt, float* __restrict__ out_bias, float* __restrict__ out_gain){
  const int co = blockIdx.x, t = threadIdx.x;
  float kv[9], gv[9];
  float s1=0.f, s2=0.f, sg=0.f, sgk=0.f;
  #pragma unroll
  for (int i=0;i<9;i++){
    const int m = t + i*128;
    const float k_ = kern[(size_t)m*128 + co];
    const float g_ = raw [(size_t)m*128 + co];
    kv[i]=k_; gv[i]=g_;
    s1 += k_; s2 += k_*k_; sg += g_; sgk += g_*k_;
  }
  __shared__ float red[4][128];
  red[0][t]=s1; red[1][t]=s2; red[2][t]=sg; red[3][t]=sgk;
  __syncthreads();
  for (int off=64; off>0; off>>=1){
    if (t < off){
      red[0][t]+=red[0][t+off]; red[1][t]+=red[1][t+off];
      red[2][t]+=red[2][t+off]; red[3][t]+=red[3][t+off];
    }
    __syncthreads();
  }
  const float N = 1152.f;
  const float S1=red[0][0], S2=red[1][0], Sg=red[2][0], Sgk=red[3][0];
  const float mu = S1/N;
  const float var = S2/N - mu*mu;
  const float mvar = N*var;
  const float maxvar = fmaxf(mvar, 1e-4f);
  const float sqrtvar = sqrtf(maxvar);
  const float ivar = 1.f/sqrtvar;
  const float g = gain[co];
  const float givar = g*ivar;
  const float dgivar = Sgk - mu*Sg;
  const float divar = dgivar*g;
  const float dsqrtvar = -divar/maxvar;
  const float dmaxvar = 0.5f*dsqrtvar/sqrtvar;
  const float dsq = bmap[co]*dmaxvar;
  const float dmu = -(givar*Sg + 2.f*dsq*(S1 - N*mu));
  const float dmuN = dmu*(1.f/N);
  #pragma unroll
  for (int i=0;i<9;i++){
    const int m = t + i*128;
    out_wt[(size_t)m*128 + co] = gv[i]*givar + 2.f*(kv[i]-mu)*dsq + dmuN;
  }
  if (t == 0){ out_gain[co] = dgivar*ivar; out_bias[co] = biasA[co]; }
}

extern "C" void kernel_launch(void* const* d_in, const int* in_sizes, int n_in,
                              void* d_out, int out_size, void* d_ws, size_t ws_size,
                              hipStream_t stream){
  const float* go   = (const float*)d_in[0];
  const float* inp  = (const float*)d_in[1];
  const float* kern = (const float*)d_in[2];
  const float* stdk = (const float*)d_in[3];
  const float* gain = (const float*)d_in[4];
  const float* bmap = (const float*)d_in[5];

  char* ws = (char*)d_ws;
  __bf16* goT   = (__bf16*)(ws + 0);                 // 51,380,224 B
  float*  raw   = (float*) (ws + 51380224);          //    589,824 B
  float*  biasA = (float*) (ws + 51970048);          //        512 B
  __bf16* stdkb = (__bf16*)(ws + 51970560);          //    294,912 B
  char*   guard =           ws + 52265472;           //        256 B (zero guard; also glds zero-src)
  __bf16* inT   = (__bf16*)(ws + 52265728);          // 60,817,408 B  (total ~113.1 MB)

  hipMemsetAsync(raw,   0, 589824, stream);
  hipMemsetAsync(biasA, 0, 512, stream);
  hipMemsetAsync(guard, 0, 256 + 60817408, stream);  // guard + full padded input

  k_cvt   <<<144, 256, 0, stream>>>(stdk, stdkb);
  k_goT   <<<3136, 256, 0, stream>>>(go, goT, biasA);
  k_inT   <<<3136, 256, 0, stream>>>(inp, inT);
  k_gradin<<<3136, 256, 0, stream>>>(go, stdkb, (float*)d_out);
  k_gradwt2<<<dim3(64,8), 256, 0, stream>>>(goT, inT, (const __bf16*)guard, raw);

  float* out = (float*)d_out;
  k_std<<<128, 128, 0, stream>>>(raw, kern, gain, bmap, biasA,
                                 out + GI_ELEMS,
                                 out + GI_ELEMS + 147456,
                                 out + GI_ELEMS + 147456 + 128);
}

// Round 3
// 376.308 us; speedup vs baseline: 3.5385x; 2.2087x over previous
//
#include <hip/hip_runtime.h>
#include <hip/hip_bf16.h>

typedef __bf16 bf16x8 __attribute__((ext_vector_type(8)));
typedef __bf16 bf16x4 __attribute__((ext_vector_type(4)));
typedef float  f32x4  __attribute__((ext_vector_type(4)));
typedef unsigned int u32;

#define HW_   3136            // 56*56
#define NPIX  200704          // 64*56*56
#define GI_ELEMS 25690112     // NPIX*128

__device__ __forceinline__ f32x4 mfma16(bf16x8 a, bf16x8 b, f32x4 c){
  return __builtin_amdgcn_mfma_f32_16x16x32_bf16(a, b, c, 0, 0, 0);
}

__device__ __forceinline__ void async16(const __bf16* g, __bf16* l){
  __builtin_amdgcn_global_load_lds(
      (const __attribute__((address_space(1))) void*)g,
      (__attribute__((address_space(3))) void*)l, 16, 0, 0);
}

// ---------------- std_kernels fp32 -> fragment-linear bf16 (for k_gradin3) ----------------
// stdkF[(((tap*4+kc)*8+j)*64 + l)*8 + e] = std[tap][ci=j*16+(l&15)][co=kc*32+(l>>4)*8+e]
__global__ __launch_bounds__(256) void k_prep(const float* __restrict__ s, __bf16* __restrict__ d){
  const int g = blockIdx.x*256 + threadIdx.x;   // 0..18431
  const int l = g & 63;
  const int j = (g >> 6) & 7;
  const int kc = (g >> 9) & 3;
  const int tap = g >> 11;
  const int ci = j*16 + (l & 15);
  const int co0 = kc*32 + (l >> 4)*8;
  const float* src = s + ((size_t)(tap*128 + ci))*128 + co0;
  f32x4 x0 = *(const f32x4*)src;
  f32x4 x1 = *(const f32x4*)(src + 4);
  bf16x8 y;
  #pragma unroll
  for (int e=0;e<4;e++){ y[e] = (__bf16)x0[e]; y[e+4] = (__bf16)x1[e]; }
  *(bf16x8*)(d + (size_t)g*8) = y;
}

// ---------------- go -> goT (bf16 [co][pix]) + goB (bf16 NHWC) + bias partials ----------------
__global__ __launch_bounds__(256) void k_goT(const float* __restrict__ go,
                                             __bf16* __restrict__ goT,
                                             __bf16* __restrict__ goB,
                                             float* __restrict__ biasA){
  __shared__ __bf16 ldsT[128][72];
  __shared__ float biasS[128];
  const int t = threadIdx.x;
  const size_t p0 = (size_t)blockIdx.x*64;
  if (t < 128) biasS[t] = 0.f;
  __syncthreads();
  float bs[4] = {0.f,0.f,0.f,0.f};
  const int co0 = (t*4) & 127;
  #pragma unroll
  for (int i=0;i<8;i++){
    const int flat = (i*256+t)*4;
    const int pl = flat >> 7; const int co = flat & 127;
    f32x4 x = *(const f32x4*)(go + p0*128 + flat);
    bf16x4 y;
    #pragma unroll
    for (int e=0;e<4;e++){ ldsT[co+e][pl] = (__bf16)x[e]; bs[e] += x[e]; y[e] = (__bf16)x[e]; }
    *(bf16x4*)(goB + p0*128 + flat) = y;
  }
  #pragma unroll
  for (int e=0;e<4;e++) atomicAdd(&biasS[co0+e], bs[e]);
  __syncthreads();
  #pragma unroll
  for (int j=0;j<2;j++){
    const int task = t + j*256; const int co = task>>2; const int ch = task&3;
    bf16x8 v0 = *(const bf16x8*)&ldsT[co][ch*16];
    bf16x8 v1 = *(const bf16x8*)&ldsT[co][ch*16+8];
    __bf16* d = goT + (size_t)co*NPIX + p0 + ch*16;
    *(bf16x8*)d = v0; *(bf16x8*)(d+8) = v1;
  }
  if (t < 128) atomicAdd(&biasA[t], biasS[t]);
}

// ---------------- inputs -> inTpad (bf16 [ci][b][58][64], interior at [h+1][w]) ----------------
__global__ __launch_bounds__(256) void k_inT(const float* __restrict__ inp,
                                             __bf16* __restrict__ inT){
  __shared__ float ldsT[128][72];
  const int t = threadIdx.x;
  const size_t p0 = (size_t)blockIdx.x*64;
  #pragma unroll
  for (int i=0;i<8;i++){
    const int flat = (i*256+t)*4;
    const int pl = flat >> 7; const int ci = flat & 127;
    f32x4 x = *(const f32x4*)(inp + p0*128 + flat);
    #pragma unroll
    for (int e=0;e<4;e++) ldsT[ci+e][pl] = x[e];
  }
  __syncthreads();
  #pragma unroll
  for (int j=0;j<4;j++){
    const int task = t + j*256; const int ci = task>>3; const int ch = task&7;
    const int p = (int)p0 + ch*8;
    const int b = p / HW_; const int r = p - b*HW_;
    const int h = r / 56;  const int w = r - h*56;
    bf16x8 pk;
    #pragma unroll
    for (int e=0;e<8;e++) pk[e] = (__bf16)ldsT[ci][ch*8+e];
    *(bf16x8*)(inT + (((size_t)(ci*64+b))*58 + (h+1))*64 + w) = pk;
  }
}

// ---------------- grad_in v3: LDS-staged A, fragment-linear B, j=8 ----------------
// grid (64 b, 7 row-chunks of 8 rows). block = 256 thr = 4 waves; wave = 112 px x 128 ci.
// LDS: 10 rows x 58 wp x 128 co bf16 = 148480 B; pixel-slot s = r*58+wp;
// byte addr of (s, co-chunk c) = s*256 + ((c ^ (s&7))<<4)  [XOR swizzle, both sides].
__global__ __launch_bounds__(256, 1) void k_gradin3(const __bf16* __restrict__ goB,
                                                    const __bf16* __restrict__ stdkF,
                                                    const __bf16* __restrict__ zsrc,
                                                    float* __restrict__ out){
  __shared__ char LDS[148480];
  const int t = threadIdx.x;
  const int wv = t >> 6, l = t & 63, lr = l & 15, lg = l >> 4;
  const int b = blockIdx.x, h0 = blockIdx.y*8;

  // ---- stage: 9280 16B chunks, linear LDS dest, inverse-swizzled global source ----
  #pragma unroll
  for (int it=0; it<37; ++it){
    const int qb = it*256 + wv*64;
    if (qb < 9280){
      const u32 q = qb + l;
      const u32 r = q / 928u;              // 58*16 chunks per row
      const u32 rem = q - r*928u;
      const u32 wp = rem >> 4;
      const u32 c = rem & 15u;
      const int h = h0 - 1 + (int)r;
      const u32 s = r*58u + wp;
      const u32 csrc = c ^ (s & 7u);
      const bool valid = (h >= 0) & (h < 56) & (wp >= 1u) & (wp <= 56u);
      const __bf16* src = valid
        ? goB + ((size_t)((b*HW_) + h*56 + ((int)wp - 1))*128 + csrc*8)
        : zsrc;
      async16(src, (__bf16*)(LDS + qb*16));
    }
  }

  // ---- per-lane pixel-slot bases for the 7 tiles ----
  int sb[7];
  #pragma unroll
  for (int tile=0; tile<7; ++tile){
    const int p = wv*112 + tile*16 + lr;   // local pixel 0..447
    const int ro = p / 56; const int w = p - ro*56;
    sb[tile] = (ro + 2)*58 + (w + 2);      // s for tap (u=0,v=0)
  }

  f32x4 acc[7][8];
  #pragma unroll
  for (int i=0;i<7;i++){
    #pragma unroll
    for (int j=0;j<8;j++){
      #pragma unroll
      for (int r=0;r<4;r++) acc[i][j][r] = 0.f;
    }
  }
  __syncthreads();

  for (int tap=0; tap<9; ++tap){
    const int u = tap/3;
    const int soff = u*58 + (tap - u*3);   // u*58 + v
    #pragma unroll
    for (int kc=0; kc<4; ++kc){
      bf16x8 Bf[8];
      #pragma unroll
      for (int j=0;j<8;++j)
        Bf[j] = *(const bf16x8*)(stdkF + ((size_t)(((tap*4 + kc)*8 + j)*64 + l))*8);
      bf16x8 Af[7];
      #pragma unroll
      for (int tile=0;tile<7;++tile){
        const int s = sb[tile] - soff;
        const int byte = (s << 8) | (((kc*4 + lg) ^ (s & 7)) << 4);
        Af[tile] = *(const bf16x8*)(LDS + byte);
      }
      #pragma unroll
      for (int tile=0;tile<7;++tile){
        #pragma unroll
        for (int j=0;j<8;++j)
          acc[tile][j] = mfma16(Af[tile], Bf[j], acc[tile][j]);
      }
    }
  }

  float* o = out + ((size_t)b*HW_ + (size_t)h0*56 + wv*112)*128;
  #pragma unroll
  for (int tile=0;tile<7;++tile){
    #pragma unroll
    for (int j=0;j<8;++j){
      #pragma unroll
      for (int r=0;r<4;++r)
        o[(size_t)(tile*16 + 4*lg + r)*128 + j*16 + lr] = acc[tile][j][r];
    }
  }
}

// ---------------- grad_wt_raw v2: all 9 taps per block, LDS double-buffered ----------------
#define BOFF0 0
#define BOFF1 29696
#define AOFF0 59424
#define AOFF1 65728

__device__ __forceinline__ void stage_chunk(const __bf16* __restrict__ goT,
                                            const __bf16* __restrict__ inT,
                                            const __bf16* __restrict__ zsrc,
                                            __bf16* lds, int boff, int aoff,
                                            int b, int ci0, int c, int w, int l){
  const int pixbase = b*HW_ + c*224;
  const int pr0 = c*4;
  #pragma unroll
  for (int i=0;i<15;++i){
    const int cbase = i*256 + w*64;
    if (cbase < 3712){
      const int chunk = cbase + l;
      const int co = chunk / 29;
      const int part = chunk - co*29;
      const __bf16* src = (part < 28) ? (goT + (size_t)co*NPIX + pixbase + part*8) : zsrc;
      async16(src, lds + boff + cbase*8);
    }
  }
  #pragma unroll
  for (int i=0;i<4;++i){
    const int cbase = i*256 + w*64;
    const int chunk = cbase + l;
    if (chunk < 784){
      const int ci = chunk / 49;
      const int r = chunk - ci*49;
      const __bf16* src = (r < 48)
        ? (inT + (((size_t)((ci0+ci)*64 + b))*58 + (pr0 + (r>>3)))*64 + (r&7)*8)
        : zsrc;
      async16(src, lds + aoff + cbase*8);
    }
  }
}

__global__ __launch_bounds__(256, 1) void k_gradwt2(const __bf16* __restrict__ goT,
                                                    const __bf16* __restrict__ inT,
                                                    const __bf16* __restrict__ zsrc,
                                                    float* __restrict__ raw){
  __shared__ __bf16 LDS[72000];
  const int t = threadIdx.x;
  const int w = t >> 6, l = t & 63, lr = l & 15, lg = l >> 4;
  const int b = blockIdx.x, ci0 = blockIdx.y*16;
  const int wco = w*32;

  if (t < 32){ LDS[AOFF0-32+t] = (__bf16)0.f; LDS[AOFF1-32+t] = (__bf16)0.f; }

  f32x4 acc[9][2];
  #pragma unroll
  for (int tp=0;tp<9;tp++){
    #pragma unroll
    for (int j=0;j<2;j++){
      #pragma unroll
      for (int r=0;r<4;r++) acc[tp][j][r] = 0.f;
    }
  }

  stage_chunk(goT, inT, zsrc, LDS, BOFF0, AOFF0, b, ci0, 0, w, l);
  __syncthreads();

  int buf = 0;
  for (int c=0; c<14; ++c){
    if (c < 13)
      stage_chunk(goT, inT, zsrc, LDS, buf ? BOFF0 : BOFF1, buf ? AOFF0 : AOFF1,
                  b, ci0, c+1, w, l);
    const __bf16* Bb = LDS + (buf ? BOFF1 : BOFF0);
    const __bf16* Ab = LDS + (buf ? AOFF1 : AOFF0);
    #pragma unroll
    for (int ks=0; ks<7; ++ks){
      const int pl = ks*32 + lg*8;
      const int q  = ks*4 + lg;
      const int hl = q / 7;
      const int w0 = pl - hl*56;
      bf16x8 b0 = *(const bf16x8*)&Bb[(wco + lr)*232 + pl];
      bf16x8 b1 = *(const bf16x8*)&Bb[(wco + 16 + lr)*232 + pl];
      const __bf16* abase = &Ab[lr*392 + hl*64 + w0];
      #pragma unroll
      for (int u=0; u<3; ++u){
        const __bf16* ap = abase + u*64;
        union { bf16x8 v; u32 d[4]; } va, a0, a2;
        va.v = *(const bf16x8*)ap;
        const u32 m1 = *(const unsigned short*)(ap - 1);
        const u32 p8 = *(const unsigned short*)(ap + 8);
        a0.d[0] = (va.d[0] << 16) | m1;
        a0.d[1] = (va.d[1] << 16) | (va.d[0] >> 16);
        a0.d[2] = (va.d[2] << 16) | (va.d[1] >> 16);
        a0.d[3] = (va.d[3] << 16) | (va.d[2] >> 16);
        a2.d[0] = (va.d[0] >> 16) | (va.d[1] << 16);
        a2.d[1] = (va.d[1] >> 16) | (va.d[2] << 16);
        a2.d[2] = (va.d[2] >> 16) | (va.d[3] << 16);
        a2.d[3] = (va.d[3] >> 16) | (p8 << 16);
        acc[u*3+0][0] = mfma16(a0.v, b0, acc[u*3+0][0]);
        acc[u*3+0][1] = mfma16(a0.v, b1, acc[u*3+0][1]);
        acc[u*3+1][0] = mfma16(va.v, b0, acc[u*3+1][0]);
        acc[u*3+1][1] = mfma16(va.v, b1, acc[u*3+1][1]);
        acc[u*3+2][0] = mfma16(a2.v, b0, acc[u*3+2][0]);
        acc[u*3+2][1] = mfma16(a2.v, b1, acc[u*3+2][1]);
      }
    }
    __syncthreads();
    buf ^= 1;
  }

  #pragma unroll
  for (int tp=0;tp<9;tp++){
    #pragma unroll
    for (int j=0;j<2;j++){
      #pragma unroll
      for (int r=0;r<4;r++)
        atomicAdd(&raw[(size_t)(tp*128 + ci0 + 4*lg + r)*128 + wco + j*16 + lr],
                  acc[tp][j][r]);
    }
  }
}

// ---------------- weight-standardization backward chain + bias/gain ----------------
__global__ __launch_bounds__(128) void k_std(const float* __restrict__ raw,
      const float* __restrict__ kern, const float* __restrict__ gain,
      const float* __restrict__ bmap, const float* __restrict__ biasA,
      float* __restrict__ out_wt, float* __restrict__ out_bias, float* __restrict__ out_gain){
  const int co = blockIdx.x, t = threadIdx.x;
  float kv[9], gv[9];
  float s1=0.f, s2=0.f, sg=0.f, sgk=0.f;
  #pragma unroll
  for (int i=0;i<9;i++){
    const int m = t + i*128;
    const float k_ = kern[(size_t)m*128 + co];
    const float g_ = raw [(size_t)m*128 + co];
    kv[i]=k_; gv[i]=g_;
    s1 += k_; s2 += k_*k_; sg += g_; sgk += g_*k_;
  }
  __shared__ float red[4][128];
  red[0][t]=s1; red[1][t]=s2; red[2][t]=sg; red[3][t]=sgk;
  __syncthreads();
  for (int off=64; off>0; off>>=1){
    if (t < off){
      red[0][t]+=red[0][t+off]; red[1][t]+=red[1][t+off];
      red[2][t]+=red[2][t+off]; red[3][t]+=red[3][t+off];
    }
    __syncthreads();
  }
  const float N = 1152.f;
  const float S1=red[0][0], S2=red[1][0], Sg=red[2][0], Sgk=red[3][0];
  const float mu = S1/N;
  const float var = S2/N - mu*mu;
  const float mvar = N*var;
  const float maxvar = fmaxf(mvar, 1e-4f);
  const float sqrtvar = sqrtf(maxvar);
  const float ivar = 1.f/sqrtvar;
  const float g = gain[co];
  const float givar = g*ivar;
  const float dgivar = Sgk - mu*Sg;
  const float divar = dgivar*g;
  const float dsqrtvar = -divar/maxvar;
  const float dmaxvar = 0.5f*dsqrtvar/sqrtvar;
  const float dsq = bmap[co]*dmaxvar;
  const float dmu = -(givar*Sg + 2.f*dsq*(S1 - N*mu));
  const float dmuN = dmu*(1.f/N);
  #pragma unroll
  for (int i=0;i<9;i++){
    const int m = t + i*128;
    out_wt[(size_t)m*128 + co] = gv[i]*givar + 2.f*(kv[i]-mu)*dsq + dmuN;
  }
  if (t == 0){ out_gain[co] = dgivar*ivar; out_bias[co] = biasA[co]; }
}

extern "C" void kernel_launch(void* const* d_in, const int* in_sizes, int n_in,
                              void* d_out, int out_size, void* d_ws, size_t ws_size,
                              hipStream_t stream){
  const float* go   = (const float*)d_in[0];
  const float* inp  = (const float*)d_in[1];
  const float* kern = (const float*)d_in[2];
  const float* stdk = (const float*)d_in[3];
  const float* gain = (const float*)d_in[4];
  const float* bmap = (const float*)d_in[5];

  char* ws = (char*)d_ws;
  __bf16* goT   = (__bf16*)(ws + 0);                 // 51,380,224 B
  float*  raw   = (float*) (ws + 51380224);          //    589,824 B
  float*  biasA = (float*) (ws + 51970048);          //        512 B
  __bf16* stdkF = (__bf16*)(ws + 51970560);          //    294,912 B
  char*   guard =           ws + 52265472;           //        256 B (zeros; glds zero-src)
  // X region: goB (51,380,224 B) first, later OVERWRITTEN by inT (60,817,408 B)
  __bf16* goB   = (__bf16*)(ws + 52265728);
  __bf16* inT   = (__bf16*)(ws + 52265728);          // total ws use: 113,083,136 B

  hipMemsetAsync(raw,   0, 589824, stream);
  hipMemsetAsync(biasA, 0, 512, stream);
  hipMemsetAsync(guard, 0, 256, stream);

  k_prep  <<<72, 256, 0, stream>>>(stdk, stdkF);
  k_goT   <<<3136, 256, 0, stream>>>(go, goT, goB, biasA);
  k_gradin3<<<dim3(64,7), 256, 0, stream>>>(goB, stdkF, (const __bf16*)guard, (float*)d_out);

  // inT region overlays goB -> zero it only after gradin3 consumed goB
  hipMemsetAsync(inT, 0, 60817408, stream);
  k_inT   <<<3136, 256, 0, stream>>>(inp, inT);
  k_gradwt2<<<dim3(64,8), 256, 0, stream>>>(goT, inT, (const __bf16*)guard, raw);

  float* out = (float*)d_out;
  k_std<<<128, 128, 0, stream>>>(raw, kern, gain, bmap, biasA,
                                 out + GI_ELEMS,
                                 out + GI_ELEMS + 147456,
                                 out + GI_ELEMS + 147456 + 128);
}

// Round 4
// 329.235 us; speedup vs baseline: 4.0444x; 1.1430x over previous
//
#include <hip/hip_runtime.h>
#include <hip/hip_bf16.h>

typedef __bf16 bf16x8 __attribute__((ext_vector_type(8)));
typedef __bf16 bf16x4 __attribute__((ext_vector_type(4)));
typedef float  f32x4  __attribute__((ext_vector_type(4)));
typedef unsigned int u32;

#define HW_   3136            // 56*56
#define NPIX  200704          // 64*56*56
#define GI_ELEMS 25690112     // NPIX*128

// ---- workspace byte offsets ----
#define GOT_OFF   0u           // goT bf16 [co][pix]            51,380,224
#define RAW_OFF   51380224u    // raw fp32                          589,824
#define BIASA_OFF 51970048u    // bias accum                            512
#define STDKF_OFF 51970560u    // stdkF bf16                        294,912
#define GUARD_OFF 52265472u    // zero guard (gradin3 zsrc)             256
#define ZB_OFF    52265728u    // zero strip for B-pad lanes          6,272
#define ZA_OFF    52272000u    // zero strip for A-pad lanes          7,168
#define X_OFF     52279168u    // goB (51,380,224) then inT (60,817,408)

__device__ __forceinline__ f32x4 mfma16(bf16x8 a, bf16x8 b, f32x4 c){
  return __builtin_amdgcn_mfma_f32_16x16x32_bf16(a, b, c, 0, 0, 0);
}

__device__ __forceinline__ void async16(const void* g, __bf16* l){
  __builtin_amdgcn_global_load_lds(
      (const __attribute__((address_space(1))) void*)g,
      (__attribute__((address_space(3))) void*)l, 16, 0, 0);
}

// ---------------- std_kernels fp32 -> fragment-linear bf16 (for k_gradin3) ----------------
__global__ __launch_bounds__(256) void k_prep(const float* __restrict__ s, __bf16* __restrict__ d){
  const int g = blockIdx.x*256 + threadIdx.x;   // 0..18431
  const int l = g & 63;
  const int j = (g >> 6) & 7;
  const int kc = (g >> 9) & 3;
  const int tap = g >> 11;
  const int ci = j*16 + (l & 15);
  const int co0 = kc*32 + (l >> 4)*8;
  const float* src = s + ((size_t)(tap*128 + ci))*128 + co0;
  f32x4 x0 = *(const f32x4*)src;
  f32x4 x1 = *(const f32x4*)(src + 4);
  bf16x8 y;
  #pragma unroll
  for (int e=0;e<4;e++){ y[e] = (__bf16)x0[e]; y[e+4] = (__bf16)x1[e]; }
  *(bf16x8*)(d + (size_t)g*8) = y;
}

// ---------------- go -> goT (bf16 [co][pix]) + goB (bf16 NHWC) + bias ----------------
// LDS [px][co] layout: writes contiguous (conflict-free); reads per-px across co (~2-way).
__global__ __launch_bounds__(256) void k_goT(const float* __restrict__ go,
                                             __bf16* __restrict__ goT,
                                             __bf16* __restrict__ goB,
                                             float* __restrict__ biasA){
  __shared__ __bf16 T[64][130];
  __shared__ float biasS[128];
  const int t = threadIdx.x;
  const size_t p0 = (size_t)blockIdx.x*64;
  if (t < 128) biasS[t] = 0.f;
  __syncthreads();
  float bs[4] = {0.f,0.f,0.f,0.f};
  const int co0 = (t*4) & 127;
  #pragma unroll
  for (int i=0;i<8;i++){
    const int flat = (i*256+t)*4;
    const int px = flat >> 7, co = flat & 127;
    f32x4 x = *(const f32x4*)(go + p0*128 + flat);
    bf16x4 y;
    #pragma unroll
    for (int e=0;e<4;e++){ y[e] = (__bf16)x[e]; bs[e] += x[e]; }
    *(bf16x4*)&T[px][co] = y;
    *(bf16x4*)(goB + p0*128 + flat) = y;
  }
  #pragma unroll
  for (int e=0;e<4;e++) atomicAdd(&biasS[co0+e], bs[e]);
  __syncthreads();
  #pragma unroll
  for (int j=0;j<2;j++){
    const int task = j*256 + t;
    const int co = task >> 2, q = task & 3;
    bf16x8 v0, v1;
    #pragma unroll
    for (int k=0;k<8;k++) v0[k] = T[q*16+k][co];
    #pragma unroll
    for (int k=0;k<8;k++) v1[k] = T[q*16+8+k][co];
    __bf16* d = goT + (size_t)co*NPIX + p0 + q*16;
    *(bf16x8*)d = v0; *(bf16x8*)(d+8) = v1;
  }
  if (t < 128) atomicAdd(&biasA[t], biasS[t]);
}

// ---------------- inputs -> inTpad (bf16 [ci][b][58][64], interior at [h+1][w]) ----------------
__global__ __launch_bounds__(256) void k_inT(const float* __restrict__ inp,
                                             __bf16* __restrict__ inT){
  __shared__ __bf16 T[64][130];
  const int t = threadIdx.x;
  const size_t p0 = (size_t)blockIdx.x*64;
  #pragma unroll
  for (int i=0;i<8;i++){
    const int flat = (i*256+t)*4;
    const int px = flat >> 7, ci = flat & 127;
    f32x4 x = *(const f32x4*)(inp + p0*128 + flat);
    bf16x4 y;
    #pragma unroll
    for (int e=0;e<4;e++) y[e] = (__bf16)x[e];
    *(bf16x4*)&T[px][ci] = y;
  }
  __syncthreads();
  #pragma unroll
  for (int j=0;j<4;j++){
    const int task = j*256 + t;
    const int ci = task >> 3, ch = task & 7;
    const int p = (int)p0 + ch*8;
    const int b = p / HW_; const int r = p - b*HW_;
    const int h = r / 56;  const int w = r - h*56;
    bf16x8 v;
    #pragma unroll
    for (int k=0;k<8;k++) v[k] = T[ch*8+k][ci];
    *(bf16x8*)(inT + (((size_t)(ci*64+b))*58 + (h+1))*64 + w) = v;
  }
}

// ---------------- grad_in v3: LDS-staged A, fragment-linear B, j=8 ----------------
__global__ __launch_bounds__(256, 1) void k_gradin3(const __bf16* __restrict__ goB,
                                                    const __bf16* __restrict__ stdkF,
                                                    const __bf16* __restrict__ zsrc,
                                                    float* __restrict__ out){
  __shared__ char LDS[148480];
  const int t = threadIdx.x;
  const int wv = t >> 6, l = t & 63, lr = l & 15, lg = l >> 4;
  const int b = blockIdx.x, h0 = blockIdx.y*8;

  #pragma unroll
  for (int it=0; it<37; ++it){
    const int qb = it*256 + wv*64;
    if (qb < 9280){
      const u32 q = qb + l;
      const u32 r = q / 928u;
      const u32 rem = q - r*928u;
      const u32 wp = rem >> 4;
      const u32 c = rem & 15u;
      const int h = h0 - 1 + (int)r;
      const u32 s = r*58u + wp;
      const u32 csrc = c ^ (s & 7u);
      const bool valid = (h >= 0) & (h < 56) & (wp >= 1u) & (wp <= 56u);
      const __bf16* src = valid
        ? goB + ((size_t)((b*HW_) + h*56 + ((int)wp - 1))*128 + csrc*8)
        : zsrc;
      async16(src, (__bf16*)(LDS + qb*16));
    }
  }

  int sb[7];
  #pragma unroll
  for (int tile=0; tile<7; ++tile){
    const int p = wv*112 + tile*16 + lr;
    const int ro = p / 56; const int w = p - ro*56;
    sb[tile] = (ro + 2)*58 + (w + 2);
  }

  f32x4 acc[7][8];
  #pragma unroll
  for (int i=0;i<7;i++){
    #pragma unroll
    for (int j=0;j<8;j++){
      #pragma unroll
      for (int r=0;r<4;r++) acc[i][j][r] = 0.f;
    }
  }
  __syncthreads();

  for (int tap=0; tap<9; ++tap){
    const int u = tap/3;
    const int soff = u*58 + (tap - u*3);
    #pragma unroll
    for (int kc=0; kc<4; ++kc){
      bf16x8 Bf[8];
      #pragma unroll
      for (int j=0;j<8;++j)
        Bf[j] = *(const bf16x8*)(stdkF + ((size_t)(((tap*4 + kc)*8 + j)*64 + l))*8);
      bf16x8 Af[7];
      #pragma unroll
      for (int tile=0;tile<7;++tile){
        const int s = sb[tile] - soff;
        const int byte = (s << 8) | (((kc*4 + lg) ^ (s & 7)) << 4);
        Af[tile] = *(const bf16x8*)(LDS + byte);
      }
      #pragma unroll
      for (int tile=0;tile<7;++tile){
        #pragma unroll
        for (int j=0;j<8;++j)
          acc[tile][j] = mfma16(Af[tile], Bf[j], acc[tile][j]);
      }
    }
  }

  float* o = out + ((size_t)b*HW_ + (size_t)h0*56 + wv*112)*128;
  #pragma unroll
  for (int tile=0;tile<7;++tile){
    #pragma unroll
    for (int j=0;j<8;++j){
      #pragma unroll
      for (int r=0;r<4;++r)
        o[(size_t)(tile*16 + 4*lg + r)*128 + j*16 + lr] = acc[tile][j][r];
    }
  }
}

// ---------------- grad_wt_raw v3: single-buffer 72KB -> 2 blocks/CU ----------------
// LDS elems: B[0..29695] guard[29696..29727] A[29728..35999]
#define GW_G 29696
#define GW_A 29728

__global__ __launch_bounds__(256, 2) void k_gradwt3(const char* __restrict__ ws,
                                                    float* __restrict__ raw){
  __shared__ __bf16 LDS[36000];
  const int t = threadIdx.x;
  const int w = t >> 6, l = t & 63, lr = l & 15, lg = l >> 4;
  const int b = blockIdx.x, ci0 = blockIdx.y*16;
  const int wco = w*32;

  if (t < 32) LDS[GW_G + t] = (__bf16)0.f;

  // staging offsets (u32 bytes from ws base); advance +448 (B) / +512 (A) per chunk.
  // pad lanes walk dedicated zero strips with the SAME stride (no per-lane stride regs).
  u32 boff[15];
  #pragma unroll
  for (int i=0;i<15;i++){
    const int chunk = i*256 + w*64 + l;
    const int co = chunk / 29, part = chunk - co*29;
    boff[i] = (part < 28)
      ? (GOT_OFF + (u32)(co*NPIX + b*HW_ + part*8)*2u)
      : ZB_OFF;
  }
  u32 aoff[4];
  #pragma unroll
  for (int i=0;i<4;i++){
    const int chunk = i*256 + w*64 + l;
    const int ci = chunk / 49, r = chunk - ci*49;
    aoff[i] = (r < 48)
      ? (X_OFF + (u32)((((ci0+ci)*64 + b)*58 + (r>>3))*64 + (r&7)*8)*2u)
      : ZA_OFF;
  }

  f32x4 acc[9][2];
  #pragma unroll
  for (int tp=0;tp<9;tp++){
    #pragma unroll
    for (int j=0;j<2;j++){
      #pragma unroll
      for (int r=0;r<4;r++) acc[tp][j][r] = 0.f;
    }
  }

  for (int c=0; c<14; ++c){
    #pragma unroll
    for (int i=0;i<15;i++){
      if (i < 14 || w < 2){
        async16(ws + boff[i], LDS + (i*256 + w*64)*8);
        boff[i] += 448u;
      }
    }
    #pragma unroll
    for (int i=0;i<4;i++){
      if (i < 3 || (w == 0 && l < 16)){
        async16(ws + aoff[i], LDS + GW_A + (i*256 + w*64)*8);
        aoff[i] += 512u;
      }
    }
    __syncthreads();

    const __bf16* Bb = LDS;
    const __bf16* Ab = LDS + GW_A;
    #pragma unroll
    for (int ks=0; ks<7; ++ks){
      const int pl = ks*32 + lg*8;
      const int q  = ks*4 + lg;
      const int hl = q / 7;
      const int w0 = pl - hl*56;
      bf16x8 b0 = *(const bf16x8*)&Bb[(wco + lr)*232 + pl];
      bf16x8 b1 = *(const bf16x8*)&Bb[(wco + 16 + lr)*232 + pl];
      const __bf16* abase = &Ab[lr*392 + hl*64 + w0];
      #pragma unroll
      for (int u=0; u<3; ++u){
        const __bf16* ap = abase + u*64;
        union { bf16x8 v; u32 d[4]; } va, a0, a2;
        va.v = *(const bf16x8*)ap;
        const u32 m1 = *(const unsigned short*)(ap - 1);
        const u32 p8 = *(const unsigned short*)(ap + 8);
        a0.d[0] = (va.d[0] << 16) | m1;
        a0.d[1] = (va.d[1] << 16) | (va.d[0] >> 16);
        a0.d[2] = (va.d[2] << 16) | (va.d[1] >> 16);
        a0.d[3] = (va.d[3] << 16) | (va.d[2] >> 16);
        a2.d[0] = (va.d[0] >> 16) | (va.d[1] << 16);
        a2.d[1] = (va.d[1] >> 16) | (va.d[2] << 16);
        a2.d[2] = (va.d[2] >> 16) | (va.d[3] << 16);
        a2.d[3] = (va.d[3] >> 16) | (p8 << 16);
        acc[u*3+0][0] = mfma16(a0.v, b0, acc[u*3+0][0]);
        acc[u*3+0][1] = mfma16(a0.v, b1, acc[u*3+0][1]);
        acc[u*3+1][0] = mfma16(va.v, b0, acc[u*3+1][0]);
        acc[u*3+1][1] = mfma16(va.v, b1, acc[u*3+1][1]);
        acc[u*3+2][0] = mfma16(a2.v, b0, acc[u*3+2][0]);
        acc[u*3+2][1] = mfma16(a2.v, b1, acc[u*3+2][1]);
      }
    }
    __syncthreads();
  }

  #pragma unroll
  for (int tp=0;tp<9;tp++){
    #pragma unroll
    for (int j=0;j<2;j++){
      #pragma unroll
      for (int r=0;r<4;r++)
        atomicAdd(&raw[(size_t)(tp*128 + ci0 + 4*lg + r)*128 + wco + j*16 + lr],
                  acc[tp][j][r]);
    }
  }
}

// ---------------- weight-standardization backward chain + bias/gain ----------------
__global__ __launch_bounds__(128) void k_std(const float* __restrict__ raw,
      const float* __restrict__ kern, const float* __restrict__ gain,
      const float* __restrict__ bmap, const float* __restrict__ biasA,
      float* __restrict__ out_wt, float* __restrict__ out_bias, float* __restrict__ out_gain){
  const int co = blockIdx.x, t = threadIdx.x;
  float kv[9], gv[9];
  float s1=0.f, s2=0.f, sg=0.f, sgk=0.f;
  #pragma unroll
  for (int i=0;i<9;i++){
    const int m = t + i*128;
    const float k_ = kern[(size_t)m*128 + co];
    const float g_ = raw [(size_t)m*128 + co];
    kv[i]=k_; gv[i]=g_;
    s1 += k_; s2 += k_*k_; sg += g_; sgk += g_*k_;
  }
  __shared__ float red[4][128];
  red[0][t]=s1; red[1][t]=s2; red[2][t]=sg; red[3][t]=sgk;
  __syncthreads();
  for (int off=64; off>0; off>>=1){
    if (t < off){
      red[0][t]+=red[0][t+off]; red[1][t]+=red[1][t+off];
      red[2][t]+=red[2][t+off]; red[3][t]+=red[3][t+off];
    }
    __syncthreads();
  }
  const float N = 1152.f;
  const float S1=red[0][0], S2=red[1][0], Sg=red[2][0], Sgk=red[3][0];
  const float mu = S1/N;
  const float var = S2/N - mu*mu;
  const float mvar = N*var;
  const float maxvar = fmaxf(mvar, 1e-4f);
  const float sqrtvar = sqrtf(maxvar);
  const float ivar = 1.f/sqrtvar;
  const float g = gain[co];
  const float givar = g*ivar;
  const float dgivar = Sgk - mu*Sg;
  const float divar = dgivar*g;
  const float dsqrtvar = -divar/maxvar;
  const float dmaxvar = 0.5f*dsqrtvar/sqrtvar;
  const float dsq = bmap[co]*dmaxvar;
  const float dmu = -(givar*Sg + 2.f*dsq*(S1 - N*mu));
  const float dmuN = dmu*(1.f/N);
  #pragma unroll
  for (int i=0;i<9;i++){
    const int m = t + i*128;
    out_wt[(size_t)m*128 + co] = gv[i]*givar + 2.f*(kv[i]-mu)*dsq + dmuN;
  }
  if (t == 0){ out_gain[co] = dgivar*ivar; out_bias[co] = biasA[co]; }
}

extern "C" void kernel_launch(void* const* d_in, const int* in_sizes, int n_in,
                              void* d_out, int out_size, void* d_ws, size_t ws_size,
                              hipStream_t stream){
  const float* go   = (const float*)d_in[0];
  const float* inp  = (const float*)d_in[1];
  const float* kern = (const float*)d_in[2];
  const float* stdk = (const float*)d_in[3];
  const float* gain = (const float*)d_in[4];
  const float* bmap = (const float*)d_in[5];

  char* ws = (char*)d_ws;
  __bf16* goT   = (__bf16*)(ws + GOT_OFF);
  float*  raw   = (float*) (ws + RAW_OFF);
  float*  biasA = (float*) (ws + BIASA_OFF);
  __bf16* stdkF = (__bf16*)(ws + STDKF_OFF);
  char*   guard =           ws + GUARD_OFF;
  __bf16* goB   = (__bf16*)(ws + X_OFF);
  __bf16* inT   = (__bf16*)(ws + X_OFF);   // overlays goB after gradin3

  hipMemsetAsync(ws + RAW_OFF,   0, 589824 + 512, stream);      // raw + biasA
  hipMemsetAsync(ws + GUARD_OFF, 0, 256 + 6272 + 7168, stream); // guard + ZB + ZA

  k_prep  <<<72, 256, 0, stream>>>(stdk, stdkF);
  k_goT   <<<3136, 256, 0, stream>>>(go, goT, goB, biasA);
  k_gradin3<<<dim3(64,7), 256, 0, stream>>>(goB, stdkF, (const __bf16*)guard, (float*)d_out);

  hipMemsetAsync(ws + X_OFF, 0, 60817408, stream);              // zero inT (after goB consumed)
  k_inT   <<<3136, 256, 0, stream>>>(inp, inT);
  k_gradwt3<<<dim3(64,8), 256, 0, stream>>>((const char*)ws, raw);

  float* out = (float*)d_out;
  k_std<<<128, 128, 0, stream>>>(raw, kern, gain, bmap, biasA,
                                 out + GI_ELEMS,
                                 out + GI_ELEMS + 147456,
                                 out + GI_ELEMS + 147456 + 128);
}

// Round 5
// 302.253 us; speedup vs baseline: 4.4054x; 1.0893x over previous
//
#include <hip/hip_runtime.h>
#include <hip/hip_bf16.h>

typedef __bf16 bf16x8 __attribute__((ext_vector_type(8)));
typedef __bf16 bf16x4 __attribute__((ext_vector_type(4)));
typedef float  f32x4  __attribute__((ext_vector_type(4)));
typedef unsigned int u32;

#define HW_   3136            // 56*56
#define NPIX  200704          // 64*56*56
#define GI_ELEMS 25690112     // NPIX*128

// ---- workspace byte offsets ----
#define GOT_OFF   0u           // goT bf16 [co][pix]            51,380,224
#define RAW_OFF   51380224u    // raw fp32                          589,824
#define BIASA_OFF 51970048u    // bias accum                            512
#define STDKF_OFF 51970560u    // stdkF bf16                        294,912
#define GUARD_OFF 52265472u    // zero guard (gradin zsrc)              256
#define ZB_OFF    52265728u    // zero strip for B-pad lanes          6,272
#define ZA_OFF    52272000u    // zero strip for A-pad lanes          7,168
#define X_OFF     52279168u    // goB (51,380,224) then inT (60,817,408)

__device__ __forceinline__ f32x4 mfma16(bf16x8 a, bf16x8 b, f32x4 c){
  return __builtin_amdgcn_mfma_f32_16x16x32_bf16(a, b, c, 0, 0, 0);
}

__device__ __forceinline__ void async16(const void* g, __bf16* l){
  __builtin_amdgcn_global_load_lds(
      (const __attribute__((address_space(1))) void*)g,
      (__attribute__((address_space(3))) void*)l, 16, 0, 0);
}

// ---------------- std_kernels fp32 -> fragment-linear bf16 ----------------
__global__ __launch_bounds__(256) void k_prep(const float* __restrict__ s, __bf16* __restrict__ d){
  const int g = blockIdx.x*256 + threadIdx.x;   // 0..18431
  const int l = g & 63;
  const int j = (g >> 6) & 7;
  const int kc = (g >> 9) & 3;
  const int tap = g >> 11;
  const int ci = j*16 + (l & 15);
  const int co0 = kc*32 + (l >> 4)*8;
  const float* src = s + ((size_t)(tap*128 + ci))*128 + co0;
  f32x4 x0 = *(const f32x4*)src;
  f32x4 x1 = *(const f32x4*)(src + 4);
  bf16x8 y;
  #pragma unroll
  for (int e=0;e<4;e++){ y[e] = (__bf16)x0[e]; y[e+4] = (__bf16)x1[e]; }
  *(bf16x8*)(d + (size_t)g*8) = y;
}

// ---------------- go -> goT (bf16 [co][pix]) + goB (bf16 NHWC) + bias ----------------
__global__ __launch_bounds__(256) void k_goT(const float* __restrict__ go,
                                             __bf16* __restrict__ goT,
                                             __bf16* __restrict__ goB,
                                             float* __restrict__ biasA){
  __shared__ __bf16 T[64][130];
  __shared__ float biasS[128];
  const int t = threadIdx.x;
  const size_t p0 = (size_t)blockIdx.x*64;
  if (t < 128) biasS[t] = 0.f;
  __syncthreads();
  float bs[4] = {0.f,0.f,0.f,0.f};
  const int co0 = (t*4) & 127;
  #pragma unroll
  for (int i=0;i<8;i++){
    const int flat = (i*256+t)*4;
    const int px = flat >> 7, co = flat & 127;
    f32x4 x = *(const f32x4*)(go + p0*128 + flat);
    bf16x4 y;
    #pragma unroll
    for (int e=0;e<4;e++){ y[e] = (__bf16)x[e]; bs[e] += x[e]; }
    *(bf16x4*)&T[px][co] = y;
    *(bf16x4*)(goB + p0*128 + flat) = y;
  }
  #pragma unroll
  for (int e=0;e<4;e++) atomicAdd(&biasS[co0+e], bs[e]);
  __syncthreads();
  #pragma unroll
  for (int j=0;j<2;j++){
    const int task = j*256 + t;
    const int co = task >> 2, q = task & 3;
    bf16x8 v0, v1;
    #pragma unroll
    for (int k=0;k<8;k++) v0[k] = T[q*16+k][co];
    #pragma unroll
    for (int k=0;k<8;k++) v1[k] = T[q*16+8+k][co];
    __bf16* d = goT + (size_t)co*NPIX + p0 + q*16;
    *(bf16x8*)d = v0; *(bf16x8*)(d+8) = v1;
  }
  if (t < 128) atomicAdd(&biasA[t], biasS[t]);
}

// ---------------- inputs -> inTpad interior (bf16 [ci][b][58][64] at [h+1][w]) ----------------
__global__ __launch_bounds__(256) void k_inT(const float* __restrict__ inp,
                                             __bf16* __restrict__ inT){
  __shared__ __bf16 T[64][130];
  const int t = threadIdx.x;
  const size_t p0 = (size_t)blockIdx.x*64;
  #pragma unroll
  for (int i=0;i<8;i++){
    const int flat = (i*256+t)*4;
    const int px = flat >> 7, ci = flat & 127;
    f32x4 x = *(const f32x4*)(inp + p0*128 + flat);
    bf16x4 y;
    #pragma unroll
    for (int e=0;e<4;e++) y[e] = (__bf16)x[e];
    *(bf16x4*)&T[px][ci] = y;
  }
  __syncthreads();
  #pragma unroll
  for (int j=0;j<4;j++){
    const int task = j*256 + t;
    const int ci = task >> 3, ch = task & 7;
    const int p = (int)p0 + ch*8;
    const int b = p / HW_; const int r = p - b*HW_;
    const int h = r / 56;  const int w = r - h*56;
    bf16x8 v;
    #pragma unroll
    for (int k=0;k<8;k++) v[k] = T[ch*8+k][ci];
    *(bf16x8*)(inT + (((size_t)(ci*64+b))*58 + (h+1))*64 + w) = v;
  }
}

// ---------------- zero only the PAD cells of inT (replaces 60.8MB memset) ----------------
// per (ci,b) 58x64 tile: row 0 (8 chunks), row 57 (8 chunks), rows 1..56 col 56 (1 chunk each)
__global__ __launch_bounds__(256) void k_padz(__bf16* __restrict__ inT){
  const int g = blockIdx.x*256 + threadIdx.x;   // 0..589823
  const int pair = g / 72, k = g - pair*72;
  __bf16* base = inT + (size_t)pair*3712;
  int off;
  if (k < 8)       off = k*8;                   // row 0
  else if (k < 16) off = 57*64 + (k-8)*8;       // row 57
  else             off = (k-15)*64 + 56;        // rows 1..56, cols 56..63
  bf16x8 z = {};
  *(bf16x8*)(base + off) = z;
}

// ---------------- grad_in v4: 512 thr / 8 waves; wave = 112px x 64ci; 2 waves/SIMD ----------------
// LDS: 10 rows x 58 wp x 128 co bf16 = 148480 B; pixel-slot s = r*58+wp;
// byte addr of (s, co-chunk c) = s*256 + ((c ^ (s&7))<<4)  [XOR swizzle, both sides].
__global__ __launch_bounds__(512, 2) void k_gradin4(const __bf16* __restrict__ goB,
                                                    const __bf16* __restrict__ stdkF,
                                                    const __bf16* __restrict__ zsrc,
                                                    float* __restrict__ out){
  __shared__ char LDS[148480];
  const int t = threadIdx.x;
  const int wv = t >> 6, l = t & 63, lr = l & 15, lg = l >> 4;
  const int b = blockIdx.x, h0 = blockIdx.y*8;
  const int j0 = (wv & 1)*4;            // ci half: j-groups [j0, j0+4)
  const int pxg = (wv >> 1)*112;        // pixel group

  // ---- stage: 9280 16B chunks, linear LDS dest, inverse-swizzled global source ----
  #pragma unroll
  for (int it=0; it<19; ++it){
    const int qb = it*512 + wv*64;
    if (qb < 9280){
      const u32 q = qb + l;
      const u32 r = q / 928u;           // 58*16 chunks per row
      const u32 rem = q - r*928u;
      const u32 wp = rem >> 4;
      const u32 c = rem & 15u;
      const int h = h0 - 1 + (int)r;
      const u32 s = r*58u + wp;
      const u32 csrc = c ^ (s & 7u);
      const bool valid = (h >= 0) & (h < 56) & (wp >= 1u) & (wp <= 56u);
      const __bf16* src = valid
        ? goB + ((size_t)((b*HW_) + h*56 + ((int)wp - 1))*128 + csrc*8)
        : zsrc;
      async16(src, (__bf16*)(LDS + qb*16));
    }
  }

  int sb[7];
  #pragma unroll
  for (int tile=0; tile<7; ++tile){
    const int p = pxg + tile*16 + lr;
    const int ro = p / 56; const int w = p - ro*56;
    sb[tile] = (ro + 2)*58 + (w + 2);
  }

  f32x4 acc[7][4];
  #pragma unroll
  for (int i=0;i<7;i++){
    #pragma unroll
    for (int j=0;j<4;j++){
      #pragma unroll
      for (int r=0;r<4;r++) acc[i][j][r] = 0.f;
    }
  }
  __syncthreads();

  for (int tap=0; tap<9; ++tap){
    const int u = tap/3;
    const int soff = u*58 + (tap - u*3);
    #pragma unroll
    for (int kc=0; kc<4; ++kc){
      bf16x8 Bf[4];
      #pragma unroll
      for (int j=0;j<4;++j)
        Bf[j] = *(const bf16x8*)(stdkF + ((size_t)(((tap*4 + kc)*8 + j0 + j)*64 + l))*8);
      bf16x8 Af[7];
      #pragma unroll
      for (int tile=0;tile<7;++tile){
        const int s = sb[tile] - soff;
        const int byte = (s << 8) | (((kc*4 + lg) ^ (s & 7)) << 4);
        Af[tile] = *(const bf16x8*)(LDS + byte);
      }
      #pragma unroll
      for (int tile=0;tile<7;++tile){
        #pragma unroll
        for (int j=0;j<4;++j)
          acc[tile][j] = mfma16(Af[tile], Bf[j], acc[tile][j]);
      }
    }
  }

  float* o = out + ((size_t)b*HW_ + (size_t)h0*56 + pxg)*128;
  #pragma unroll
  for (int tile=0;tile<7;++tile){
    #pragma unroll
    for (int j=0;j<4;++j){
      #pragma unroll
      for (int r=0;r<4;++r)
        o[(size_t)(tile*16 + 4*lg + r)*128 + (j0 + j)*16 + lr] = acc[tile][j][r];
    }
  }
}

// ---------------- grad_wt_raw v3: single-buffer 72KB -> 2 blocks/CU ----------------
#define GW_G 29696
#define GW_A 29728

__global__ __launch_bounds__(256, 2) void k_gradwt3(const char* __restrict__ ws,
                                                    float* __restrict__ raw){
  __shared__ __bf16 LDS[36000];
  const int t = threadIdx.x;
  const int w = t >> 6, l = t & 63, lr = l & 15, lg = l >> 4;
  const int b = blockIdx.x, ci0 = blockIdx.y*16;
  const int wco = w*32;

  if (t < 32) LDS[GW_G + t] = (__bf16)0.f;

  u32 boff[15];
  #pragma unroll
  for (int i=0;i<15;i++){
    const int chunk = i*256 + w*64 + l;
    const int co = chunk / 29, part = chunk - co*29;
    boff[i] = (part < 28)
      ? (GOT_OFF + (u32)(co*NPIX + b*HW_ + part*8)*2u)
      : ZB_OFF;
  }
  u32 aoff[4];
  #pragma unroll
  for (int i=0;i<4;i++){
    const int chunk = i*256 + w*64 + l;
    const int ci = chunk / 49, r = chunk - ci*49;
    aoff[i] = (r < 48)
      ? (X_OFF + (u32)((((ci0+ci)*64 + b)*58 + (r>>3))*64 + (r&7)*8)*2u)
      : ZA_OFF;
  }

  f32x4 acc[9][2];
  #pragma unroll
  for (int tp=0;tp<9;tp++){
    #pragma unroll
    for (int j=0;j<2;j++){
      #pragma unroll
      for (int r=0;r<4;r++) acc[tp][j][r] = 0.f;
    }
  }

  for (int c=0; c<14; ++c){
    #pragma unroll
    for (int i=0;i<15;i++){
      if (i < 14 || w < 2){
        async16(ws + boff[i], LDS + (i*256 + w*64)*8);
        boff[i] += 448u;
      }
    }
    #pragma unroll
    for (int i=0;i<4;i++){
      if (i < 3 || (w == 0 && l < 16)){
        async16(ws + aoff[i], LDS + GW_A + (i*256 + w*64)*8);
        aoff[i] += 512u;
      }
    }
    __syncthreads();

    const __bf16* Bb = LDS;
    const __bf16* Ab = LDS + GW_A;
    #pragma unroll
    for (int ks=0; ks<7; ++ks){
      const int pl = ks*32 + lg*8;
      const int q  = ks*4 + lg;
      const int hl = q / 7;
      const int w0 = pl - hl*56;
      bf16x8 b0 = *(const bf16x8*)&Bb[(wco + lr)*232 + pl];
      bf16x8 b1 = *(const bf16x8*)&Bb[(wco + 16 + lr)*232 + pl];
      const __bf16* abase = &Ab[lr*392 + hl*64 + w0];
      #pragma unroll
      for (int u=0; u<3; ++u){
        const __bf16* ap = abase + u*64;
        union { bf16x8 v; u32 d[4]; } va, a0, a2;
        va.v = *(const bf16x8*)ap;
        const u32 m1 = *(const unsigned short*)(ap - 1);
        const u32 p8 = *(const unsigned short*)(ap + 8);
        a0.d[0] = (va.d[0] << 16) | m1;
        a0.d[1] = (va.d[1] << 16) | (va.d[0] >> 16);
        a0.d[2] = (va.d[2] << 16) | (va.d[1] >> 16);
        a0.d[3] = (va.d[3] << 16) | (va.d[2] >> 16);
        a2.d[0] = (va.d[0] >> 16) | (va.d[1] << 16);
        a2.d[1] = (va.d[1] >> 16) | (va.d[2] << 16);
        a2.d[2] = (va.d[2] >> 16) | (va.d[3] << 16);
        a2.d[3] = (va.d[3] >> 16) | (p8 << 16);
        acc[u*3+0][0] = mfma16(a0.v, b0, acc[u*3+0][0]);
        acc[u*3+0][1] = mfma16(a0.v, b1, acc[u*3+0][1]);
        acc[u*3+1][0] = mfma16(va.v, b0, acc[u*3+1][0]);
        acc[u*3+1][1] = mfma16(va.v, b1, acc[u*3+1][1]);
        acc[u*3+2][0] = mfma16(a2.v, b0, acc[u*3+2][0]);
        acc[u*3+2][1] = mfma16(a2.v, b1, acc[u*3+2][1]);
      }
    }
    __syncthreads();
  }

  #pragma unroll
  for (int tp=0;tp<9;tp++){
    #pragma unroll
    for (int j=0;j<2;j++){
      #pragma unroll
      for (int r=0;r<4;r++)
        atomicAdd(&raw[(size_t)(tp*128 + ci0 + 4*lg + r)*128 + wco + j*16 + lr],
                  acc[tp][j][r]);
    }
  }
}

// ---------------- weight-standardization backward chain + bias/gain ----------------
__global__ __launch_bounds__(128) void k_std(const float* __restrict__ raw,
      const float* __restrict__ kern, const float* __restrict__ gain,
      const float* __restrict__ bmap, const float* __restrict__ biasA,
      float* __restrict__ out_wt, float* __restrict__ out_bias, float* __restrict__ out_gain){
  const int co = blockIdx.x, t = threadIdx.x;
  float kv[9], gv[9];
  float s1=0.f, s2=0.f, sg=0.f, sgk=0.f;
  #pragma unroll
  for (int i=0;i<9;i++){
    const int m = t + i*128;
    const float k_ = kern[(size_t)m*128 + co];
    const float g_ = raw [(size_t)m*128 + co];
    kv[i]=k_; gv[i]=g_;
    s1 += k_; s2 += k_*k_; sg += g_; sgk += g_*k_;
  }
  __shared__ float red[4][128];
  red[0][t]=s1; red[1][t]=s2; red[2][t]=sg; red[3][t]=sgk;
  __syncthreads();
  for (int off=64; off>0; off>>=1){
    if (t < off){
      red[0][t]+=red[0][t+off]; red[1][t]+=red[1][t+off];
      red[2][t]+=red[2][t+off]; red[3][t]+=red[3][t+off];
    }
    __syncthreads();
  }
  const float N = 1152.f;
  const float S1=red[0][0], S2=red[1][0], Sg=red[2][0], Sgk=red[3][0];
  const float mu = S1/N;
  const float var = S2/N - mu*mu;
  const float mvar = N*var;
  const float maxvar = fmaxf(mvar, 1e-4f);
  const float sqrtvar = sqrtf(maxvar);
  const float ivar = 1.f/sqrtvar;
  const float g = gain[co];
  const float givar = g*ivar;
  const float dgivar = Sgk - mu*Sg;
  const float divar = dgivar*g;
  const float dsqrtvar = -divar/maxvar;
  const float dmaxvar = 0.5f*dsqrtvar/sqrtvar;
  const float dsq = bmap[co]*dmaxvar;
  const float dmu = -(givar*Sg + 2.f*dsq*(S1 - N*mu));
  const float dmuN = dmu*(1.f/N);
  #pragma unroll
  for (int i=0;i<9;i++){
    const int m = t + i*128;
    out_wt[(size_t)m*128 + co] = gv[i]*givar + 2.f*(kv[i]-mu)*dsq + dmuN;
  }
  if (t == 0){ out_gain[co] = dgivar*ivar; out_bias[co] = biasA[co]; }
}

extern "C" void kernel_launch(void* const* d_in, const int* in_sizes, int n_in,
                              void* d_out, int out_size, void* d_ws, size_t ws_size,
                              hipStream_t stream){
  const float* go   = (const float*)d_in[0];
  const float* inp  = (const float*)d_in[1];
  const float* kern = (const float*)d_in[2];
  const float* stdk = (const float*)d_in[3];
  const float* gain = (const float*)d_in[4];
  const float* bmap = (const float*)d_in[5];

  char* ws = (char*)d_ws;
  __bf16* goT   = (__bf16*)(ws + GOT_OFF);
  float*  raw   = (float*) (ws + RAW_OFF);
  float*  biasA = (float*) (ws + BIASA_OFF);
  __bf16* stdkF = (__bf16*)(ws + STDKF_OFF);
  char*   guard =           ws + GUARD_OFF;
  __bf16* goB   = (__bf16*)(ws + X_OFF);
  __bf16* inT   = (__bf16*)(ws + X_OFF);   // overlays goB after gradin4

  hipMemsetAsync(ws + RAW_OFF,   0, 589824 + 512, stream);      // raw + biasA
  hipMemsetAsync(ws + GUARD_OFF, 0, 256 + 6272 + 7168, stream); // guard + ZB + ZA

  k_prep  <<<72, 256, 0, stream>>>(stdk, stdkF);
  k_goT   <<<3136, 256, 0, stream>>>(go, goT, goB, biasA);
  k_gradin4<<<dim3(64,7), 512, 0, stream>>>(goB, stdkF, (const __bf16*)guard, (float*)d_out);

  // inT overlays goB -> touch only after gradin4 consumed goB
  k_padz  <<<2304, 256, 0, stream>>>(inT);
  k_inT   <<<3136, 256, 0, stream>>>(inp, inT);
  k_gradwt3<<<dim3(64,8), 256, 0, stream>>>((const char*)ws, raw);

  float* out = (float*)d_out;
  k_std<<<128, 128, 0, stream>>>(raw, kern, gain, bmap, biasA,
                                 out + GI_ELEMS,
                                 out + GI_ELEMS + 147456,
                                 out + GI_ELEMS + 147456 + 128);
}